// Round 2
// baseline (108.407 us; speedup 1.0000x reference)
//
#include <hip/hip_runtime.h>
#include <stdint.h>

#define B_   64
#define T_   8192
#define D_   128
#define L_   64
#define CH   64        // chunks per batch
#define CT   128       // tokens per chunk
#define SUB  64        // tokens per subchunk
#define REC  132       // floats per partial record: [0]=m [1]=s [4..131]=acc
#define XS   136       // LDS row stride (bf16 elems), padded vs 128

typedef float f32x4 __attribute__((ext_vector_type(4)));
typedef short s16x8 __attribute__((ext_vector_type(8)));
typedef short s16x4 __attribute__((ext_vector_type(4)));

__device__ __forceinline__ float bf2f_lo(uint32_t u) {
  union { uint32_t u; float f; } c; c.u = u << 16; return c.f;
}
__device__ __forceinline__ float bf2f_hi(uint32_t u) {
  union { uint32_t u; float f; } c; c.u = u & 0xffff0000u; return c.f;
}
__device__ __forceinline__ uint16_t f2bf(float f) {
  union { float f; uint32_t u; } c; c.f = f;
  uint32_t u = c.u;
  return (uint16_t)((u + 0x7fffu + ((u >> 16) & 1u)) >> 16);  // RNE; no NaN in data
}
__device__ __forceinline__ float bfbits2f(uint16_t h) {
  union { uint32_t u; float f; } c; c.u = ((uint32_t)h) << 16; return c.f;
}

// ---------------------------------------------------------------------------
// Kernel A: normalize lengths to int32 in ws, robust to int32 OR int64 input.
// Values are guaranteed >= 1, so int32 data has ALL words >= 1; int64 data has
// all odd 32-bit words == 0. First 256 bytes are safe to read either way.
// ---------------------------------------------------------------------------
__global__ void lennorm(const void* __restrict__ lengths_raw,
                        int* __restrict__ lens) {
  const int tid = threadIdx.x;                   // 64 threads, 1 block
  const int* s32 = (const int*)lengths_raw;
  bool odd_zero = (tid < 32) ? (s32[2 * tid + 1] == 0) : true;
  bool is64 = __all(odd_zero);
  int v;
  if (is64) v = (int)((const long long*)lengths_raw)[tid];  // safe: buffer IS 512B
  else      v = s32[tid];
  lens[tid] = v;
}

// ---------------------------------------------------------------------------
// Kernel 0: pack W_k / W_q into bf16 hi/lo MFMA B-fragment order.
// frag id = mat*32 + term*16 + w*4 + kk  (mat: 0=K 1=Q, term: 0=hi 1=lo,
// w = L-tile 0..3, kk = k-step 0..3). Each frag: 64 lanes x 8 bf16 (16 B/lane).
// B-frag mapping: n = w*16 + (lane&15); k = kk*32 + 4*(lane>>4) + (j&3) + 16*(j>>2)
// ---------------------------------------------------------------------------
__global__ void wprep(const float* __restrict__ key_w,
                      const float* __restrict__ query_w,
                      uint16_t* __restrict__ wfrag) {
  int gid  = blockIdx.x * 256 + threadIdx.x;   // 0..4095
  int lane = gid & 63;
  int frag = gid >> 6;                         // 0..63
  int kk   = frag & 3;
  int w    = (frag >> 2) & 3;
  int term = (frag >> 4) & 1;
  int mat  = frag >> 5;
  const float* src = mat ? query_w : key_w;
  int n = w * 16 + (lane & 15);
  int g = lane >> 4;
  uint16_t o[8];
#pragma unroll
  for (int j = 0; j < 8; ++j) {
    int k = kk * 32 + g * 4 + (j & 3) + 16 * (j >> 2);
    float v = src[k * L_ + n];
    uint16_t hi = f2bf(v);
    if (term == 0) o[j] = hi;
    else           o[j] = f2bf(v - bfbits2f(hi));
  }
  uint16_t* dst = wfrag + (size_t)frag * 512 + lane * 8;
#pragma unroll
  for (int j = 0; j < 8; ++j) dst[j] = o[j];
}

// ---------------------------------------------------------------------------
// Kernel 1: per (batch, 128-token chunk) online-softmax partial.
// ---------------------------------------------------------------------------
__global__ __launch_bounds__(256) void attn_partial(
    const float* __restrict__ seq, const int* __restrict__ lens,
    const uint16_t* __restrict__ wfrag, float* __restrict__ partials) {
  const int b     = blockIdx.y;
  const int chunk = blockIdx.x;
  const int tid   = threadIdx.x;
  const int len   = lens[b];
  const int cstart = chunk * CT;
  float* rec = partials + ((size_t)b * CH + chunk) * REC;

  if (cstart >= len) {                       // fully masked chunk: empty partial
    if (tid == 0) { rec[0] = -1e30f; rec[1] = 0.f; }
    if (tid < 128) rec[4 + tid] = 0.f;
    return;
  }

  __shared__ uint16_t Xhi[SUB][XS];
  __shared__ uint16_t Xlo[SUB][XS];
  __shared__ float lpart[4][64];
  __shared__ float wts[64];
  __shared__ float accred[4][128];
  __shared__ float smM, smS, smF;

  const int lane = tid & 63;
  const int wv   = tid >> 6;       // wave id = L-tile
  const int c    = lane & 15;
  const int g    = lane >> 4;

  // --- persistent W fragments for this wave's L-tile ---
  s16x8 wkh[4], wkl[4], wqh[4], wql[4];
#pragma unroll
  for (int kk = 0; kk < 4; ++kk) {
    wkh[kk] = *(const s16x8*)(wfrag + (size_t)( 0 + wv * 4 + kk) * 512 + lane * 8);
    wkl[kk] = *(const s16x8*)(wfrag + (size_t)(16 + wv * 4 + kk) * 512 + lane * 8);
    wqh[kk] = *(const s16x8*)(wfrag + (size_t)(32 + wv * 4 + kk) * 512 + lane * 8);
    wql[kk] = *(const s16x8*)(wfrag + (size_t)(48 + wv * 4 + kk) * 512 + lane * 8);
  }

  if (tid == 0) { smM = -1e30f; smS = 0.f; }
  float acc0 = 0.f, acc1 = 0.f;
  const int pr = tid & 63;         // d-pair: d = 2*pr, 2*pr+1
  const int qq = tid >> 6;         // token quarter (16 tokens)

  const int remain = len - cstart;                     // >= 1
  const int nsub = (remain > SUB) ? 2 : 1;

  for (int sub = 0; sub < nsub; ++sub) {
    const int tstart = cstart + sub * SUB;
    // ---- stage 64x128 fp32 -> bf16 hi/lo in LDS ----
    const float* sp = seq + ((size_t)b * T_ + tstart) * D_;
#pragma unroll
    for (int i = 0; i < 8; ++i) {
      int idx4 = tid + i * 256;                 // float4 index in 64x128 tile
      float4 v = ((const float4*)sp)[idx4];
      int tok = idx4 >> 5;                      // 32 float4 per row
      int d   = (idx4 & 31) * 4;
      uint16_t h0 = f2bf(v.x), h1 = f2bf(v.y), h2 = f2bf(v.z), h3 = f2bf(v.w);
      s16x4 hh = { (short)h0, (short)h1, (short)h2, (short)h3 };
      *(s16x4*)(&Xhi[tok][d]) = hh;
      uint16_t l0 = f2bf(v.x - bfbits2f(h0));
      uint16_t l1 = f2bf(v.y - bfbits2f(h1));
      uint16_t l2 = f2bf(v.z - bfbits2f(h2));
      uint16_t l3 = f2bf(v.w - bfbits2f(h3));
      s16x4 ll = { (short)l0, (short)l1, (short)l2, (short)l3 };
      *(s16x4*)(&Xlo[tok][d]) = ll;
    }
    __syncthreads();

    // ---- GEMMs: K = X Wk, Q = X Wq via split bf16 (hi*hi + hi*lo + lo*hi) ----
    f32x4 kacc[4], qacc[4];
#pragma unroll
    for (int m = 0; m < 4; ++m) {
      kacc[m] = (f32x4){0.f, 0.f, 0.f, 0.f};
      qacc[m] = (f32x4){0.f, 0.f, 0.f, 0.f};
    }
#pragma unroll
    for (int kk = 0; kk < 4; ++kk) {
#pragma unroll
      for (int m = 0; m < 4; ++m) {
        const int row = m * 16 + c;
        const int kb  = kk * 32 + g * 4;
        s16x4 a0 = *(const s16x4*)(&Xhi[row][kb]);
        s16x4 a1 = *(const s16x4*)(&Xhi[row][kb + 16]);
        s16x4 b0 = *(const s16x4*)(&Xlo[row][kb]);
        s16x4 b1 = *(const s16x4*)(&Xlo[row][kb + 16]);
        s16x8 ah = { a0[0],a0[1],a0[2],a0[3], a1[0],a1[1],a1[2],a1[3] };
        s16x8 al = { b0[0],b0[1],b0[2],b0[3], b1[0],b1[1],b1[2],b1[3] };
        kacc[m] = __builtin_amdgcn_mfma_f32_16x16x32_bf16(ah, wkh[kk], kacc[m], 0, 0, 0);
        kacc[m] = __builtin_amdgcn_mfma_f32_16x16x32_bf16(ah, wkl[kk], kacc[m], 0, 0, 0);
        kacc[m] = __builtin_amdgcn_mfma_f32_16x16x32_bf16(al, wkh[kk], kacc[m], 0, 0, 0);
        qacc[m] = __builtin_amdgcn_mfma_f32_16x16x32_bf16(ah, wqh[kk], qacc[m], 0, 0, 0);
        qacc[m] = __builtin_amdgcn_mfma_f32_16x16x32_bf16(ah, wql[kk], qacc[m], 0, 0, 0);
        qacc[m] = __builtin_amdgcn_mfma_f32_16x16x32_bf16(al, wqh[kk], qacc[m], 0, 0, 0);
      }
    }

    // ---- logits: per-lane k*q, reduce over 16 lanes (the L dim slice) ----
#pragma unroll
    for (int m = 0; m < 4; ++m) {
#pragma unroll
      for (int r = 0; r < 4; ++r) {
        float v = kacc[m][r] * qacc[m][r];
        v += __shfl_xor(v, 1);  v += __shfl_xor(v, 2);
        v += __shfl_xor(v, 4);  v += __shfl_xor(v, 8);
        if (c == 0) lpart[wv][m * 16 + g * 4 + r] = v;
      }
    }
    __syncthreads();

    // ---- online softmax update (wave 0 owns the 64 tokens) ----
    if (tid < 64) {
      float v = lpart[0][tid] + lpart[1][tid] + lpart[2][tid] + lpart[3][tid];
      float logit = ((tstart + tid) < len) ? v : -1e30f;
      float mx = logit;
      mx = fmaxf(mx, __shfl_xor(mx, 32)); mx = fmaxf(mx, __shfl_xor(mx, 16));
      mx = fmaxf(mx, __shfl_xor(mx, 8));  mx = fmaxf(mx, __shfl_xor(mx, 4));
      mx = fmaxf(mx, __shfl_xor(mx, 2));  mx = fmaxf(mx, __shfl_xor(mx, 1));
      float mOld = smM;
      float mNew = fmaxf(mOld, mx);
      float wt = __expf(logit - mNew);
      wts[tid] = wt;
      float ss = wt;
      ss += __shfl_xor(ss, 32); ss += __shfl_xor(ss, 16); ss += __shfl_xor(ss, 8);
      ss += __shfl_xor(ss, 4);  ss += __shfl_xor(ss, 2);  ss += __shfl_xor(ss, 1);
      if (tid == 0) {
        float f = __expf(mOld - mNew);
        smF = f; smS = smS * f + ss; smM = mNew;
      }
    }
    __syncthreads();

    // ---- weighted accumulation: acc[d] += w_t * x[t][d] (x = hi+lo) ----
    float f = smF;
    acc0 *= f; acc1 *= f;
#pragma unroll
    for (int t = 0; t < 16; ++t) {
      int tok = qq * 16 + t;
      uint32_t hv = *(const uint32_t*)(&Xhi[tok][pr * 2]);
      uint32_t lv = *(const uint32_t*)(&Xlo[tok][pr * 2]);
      float wt = wts[tok];
      acc0 += wt * (bf2f_lo(hv) + bf2f_lo(lv));
      acc1 += wt * (bf2f_hi(hv) + bf2f_hi(lv));
    }
    __syncthreads();
  }

  // ---- write partial record ----
  accred[qq][pr * 2]     = acc0;
  accred[qq][pr * 2 + 1] = acc1;
  __syncthreads();
  if (tid < 128)
    rec[4 + tid] = accred[0][tid] + accred[1][tid] + accred[2][tid] + accred[3][tid];
  if (tid == 0) { rec[0] = smM; rec[1] = smS; }
}

// ---------------------------------------------------------------------------
// Kernel 2: merge the 64 chunk-partials per batch, add bias.
// ---------------------------------------------------------------------------
__global__ void attn_combine(const float* __restrict__ partials,
                             const float* __restrict__ bias,
                             float* __restrict__ out) {
  int b = blockIdx.x;
  int tid = threadIdx.x;                       // 128 threads = D
  const float* base = partials + (size_t)b * CH * REC;
  float M = -1e30f;
  for (int i = 0; i < CH; ++i) M = fmaxf(M, base[i * REC]);
  float S = 0.f;
  for (int i = 0; i < CH; ++i) S += __expf(base[i * REC] - M) * base[i * REC + 1];
  float num = 0.f;
  for (int i = 0; i < CH; ++i) num += __expf(base[i * REC] - M) * base[i * REC + 4 + tid];
  float r = (S > 0.f) ? (num / S) : 0.f;       // guard: never 0/0
  out[b * D_ + tid] = r + bias[tid];
}

extern "C" void kernel_launch(void* const* d_in, const int* in_sizes, int n_in,
                              void* d_out, int out_size, void* d_ws, size_t ws_size,
                              hipStream_t stream) {
  const float* seq     = (const float*)d_in[0];
  const void*  len_raw = d_in[1];
  const float* key_w   = (const float*)d_in[2];
  const float* query_w = (const float*)d_in[3];
  const float* bias    = (const float*)d_in[4];
  float*       out     = (float*)d_out;

  uint16_t* wfrag    = (uint16_t*)d_ws;              // 64 KB fragment table
  float*    partials = (float*)((char*)d_ws + 65536);        // 64*64*132 fl ≈ 2.1 MB
  int*      lens     = (int*)((char*)d_ws + 65536 + 2162688);

  lennorm<<<dim3(1), dim3(64), 0, stream>>>(len_raw, lens);
  wprep<<<dim3(16), dim3(256), 0, stream>>>(key_w, query_w, wfrag);
  attn_partial<<<dim3(CH, B_), dim3(256), 0, stream>>>(seq, lens, wfrag, partials);
  attn_combine<<<dim3(B_), dim3(128), 0, stream>>>(partials, bias, out);
}

// Round 3
// 98.053 us; speedup vs baseline: 1.1056x; 1.1056x over previous
//
#include <hip/hip_runtime.h>
#include <stdint.h>

#define B_   64
#define T_   8192
#define D_   128
#define L_   64
#define CH   64        // chunks per batch
#define CT   128       // tokens per chunk
#define SUB  64        // tokens per subchunk
#define REC  132       // floats per partial record: [0]=m [1]=s [4..131]=acc
#define NXB  16        // x-blocks per batch; chunks per block = CH/NXB = 4
#define XSF  136       // padded LDS row stride (bf16 elems) for frag-layout X

typedef float f32x4 __attribute__((ext_vector_type(4)));
typedef short s16x8 __attribute__((ext_vector_type(8)));
typedef short s16x4 __attribute__((ext_vector_type(4)));

__device__ __forceinline__ uint16_t f2bf(float f) {
  union { float f; uint32_t u; } c; c.f = f;
  uint32_t u = c.u;
  return (uint16_t)((u + 0x7fffu + ((u >> 16) & 1u)) >> 16);  // RNE; data has no NaN
}
__device__ __forceinline__ float bfbits2f(uint16_t h) {
  union { uint32_t u; float f; } c; c.u = ((uint32_t)h) << 16; return c.f;
}

// ---------------------------------------------------------------------------
// prep: blocks 0..15 pack W_k/W_q into bf16 hi/lo MFMA B-fragment order;
// block 16 normalizes lengths (robust to int32 OR int64 input).
// B-frag mapping: n = w*16 + (lane&15); k = kk*32 + 4*(lane>>4) + (j&3) + 16*(j>>2)
// frag id = mat*32 + term*16 + w*4 + kk.
// ---------------------------------------------------------------------------
__global__ void prep(const float* __restrict__ key_w,
                     const float* __restrict__ query_w,
                     const void* __restrict__ lengths_raw,
                     uint16_t* __restrict__ wfrag,
                     int* __restrict__ lens) {
  if (blockIdx.x == 16) {
    const int tid = threadIdx.x;
    if (tid >= 64) return;                       // single wave does the work
    const int* s32 = (const int*)lengths_raw;
    bool odd_zero = (tid < 32) ? (s32[2 * tid + 1] == 0) : true;
    bool is64 = __all(odd_zero);
    int v;
    if (is64) v = (int)((const long long*)lengths_raw)[tid];
    else      v = s32[tid];
    lens[tid] = v;
    return;
  }
  int gid  = blockIdx.x * 256 + threadIdx.x;   // 0..4095
  int lane = gid & 63;
  int frag = gid >> 6;                         // 0..63
  int kk   = frag & 3;
  int w    = (frag >> 2) & 3;
  int term = (frag >> 4) & 1;
  int mat  = frag >> 5;
  const float* src = mat ? query_w : key_w;
  int n = w * 16 + (lane & 15);
  int g = lane >> 4;
  uint16_t o[8];
#pragma unroll
  for (int j = 0; j < 8; ++j) {
    int k = kk * 32 + g * 4 + (j & 3) + 16 * (j >> 2);
    float v = src[k * L_ + n];
    uint16_t hi = f2bf(v);
    if (term == 0) o[j] = hi;
    else           o[j] = f2bf(v - bfbits2f(hi));
  }
  uint16_t* dst = wfrag + (size_t)frag * 512 + lane * 8;
#pragma unroll
  for (int j = 0; j < 8; ++j) dst[j] = o[j];
}

// ---------------------------------------------------------------------------
// One 64-token subchunk: convert regs->LDS (frag-contiguous layout), optional
// prefetch of the next subchunk, MFMA K/Q GEMMs (error-compensated bf16),
// logits, all-wave redundant online softmax, fp32 register pooling.
// ---------------------------------------------------------------------------
template <bool PREF>
__device__ __forceinline__ void do_sub(
    const f32x4 (&v)[8], f32x4 (&vn)[8], const float* __restrict__ spNext,
    int tid, int lane, int wv, int tstart, int len,
    uint16_t* __restrict__ XFhi, uint16_t* __restrict__ XFlo,
    float (*__restrict__ lpart)[64], float* __restrict__ wts,
    const s16x8* wkh, const s16x8* wkl, const s16x8* wqh, const s16x8* wql,
    float& M, float& Ssum, f32x4& pacc) {
  const int tokb = tid >> 5;                         // tok = tokb + 8*i
  // permuted in-row offset: d0=(tid&31)*4 -> p0 so A-frag reads are contiguous
  const int p0 = ((tid >> 3) & 3) * 32 + (tid & 3) * 8 + ((tid >> 2) & 1) * 4;

  if (PREF) {                                        // issue next-sub loads first
#pragma unroll
    for (int i = 0; i < 8; ++i)
      vn[i] = ((const f32x4*)spNext)[tid + i * 256];
  }

  // ---- convert fp32 -> bf16 hi/lo, store in frag-contiguous LDS layout ----
#pragma unroll
  for (int i = 0; i < 8; ++i) {
    int tok = tokb + i * 8;
    f32x4 x = v[i];
    uint16_t h0 = f2bf(x[0]), h1 = f2bf(x[1]), h2 = f2bf(x[2]), h3 = f2bf(x[3]);
    *(s16x4*)(&XFhi[tok * XSF + p0]) = (s16x4){(short)h0, (short)h1, (short)h2, (short)h3};
    uint16_t l0 = f2bf(x[0] - bfbits2f(h0));
    uint16_t l1 = f2bf(x[1] - bfbits2f(h1));
    uint16_t l2 = f2bf(x[2] - bfbits2f(h2));
    uint16_t l3 = f2bf(x[3] - bfbits2f(h3));
    *(s16x4*)(&XFlo[tok * XSF + p0]) = (s16x4){(short)l0, (short)l1, (short)l2, (short)l3};
  }
  __syncthreads();

  // ---- K = X Wk, Q = X Wq (hi*hi + hi*lo + lo*hi) ----
  const int c  = lane & 15;
  const int g2 = lane >> 4;
  f32x4 kacc[4], qacc[4];
#pragma unroll
  for (int m = 0; m < 4; ++m) {
    kacc[m] = (f32x4){0.f, 0.f, 0.f, 0.f};
    qacc[m] = (f32x4){0.f, 0.f, 0.f, 0.f};
  }
#pragma unroll
  for (int kk = 0; kk < 4; ++kk) {
#pragma unroll
    for (int m = 0; m < 4; ++m) {
      const int eo = (m * 16 + c) * XSF + kk * 32 + g2 * 8;
      s16x8 ah = *(const s16x8*)(&XFhi[eo]);
      s16x8 al = *(const s16x8*)(&XFlo[eo]);
      kacc[m] = __builtin_amdgcn_mfma_f32_16x16x32_bf16(ah, wkh[kk], kacc[m], 0, 0, 0);
      kacc[m] = __builtin_amdgcn_mfma_f32_16x16x32_bf16(ah, wkl[kk], kacc[m], 0, 0, 0);
      kacc[m] = __builtin_amdgcn_mfma_f32_16x16x32_bf16(al, wkh[kk], kacc[m], 0, 0, 0);
      qacc[m] = __builtin_amdgcn_mfma_f32_16x16x32_bf16(ah, wqh[kk], qacc[m], 0, 0, 0);
      qacc[m] = __builtin_amdgcn_mfma_f32_16x16x32_bf16(ah, wql[kk], qacc[m], 0, 0, 0);
      qacc[m] = __builtin_amdgcn_mfma_f32_16x16x32_bf16(al, wqh[kk], qacc[m], 0, 0, 0);
    }
  }

  // ---- logits: k*q, reduce over the 16-lane L-slice ----
#pragma unroll
  for (int m = 0; m < 4; ++m) {
#pragma unroll
    for (int r = 0; r < 4; ++r) {
      float val = kacc[m][r] * qacc[m][r];
      val += __shfl_xor(val, 1); val += __shfl_xor(val, 2);
      val += __shfl_xor(val, 4); val += __shfl_xor(val, 8);
      if (c == 0) lpart[wv][m * 16 + g2 * 4 + r] = val;
    }
  }
  __syncthreads();

  // ---- online softmax: ALL waves compute redundantly (register state) ----
  float logit = lpart[0][lane] + lpart[1][lane] + lpart[2][lane] + lpart[3][lane];
  logit = (tstart + lane < len) ? logit : -1e30f;
  float mx = logit;
  mx = fmaxf(mx, __shfl_xor(mx, 32)); mx = fmaxf(mx, __shfl_xor(mx, 16));
  mx = fmaxf(mx, __shfl_xor(mx, 8));  mx = fmaxf(mx, __shfl_xor(mx, 4));
  mx = fmaxf(mx, __shfl_xor(mx, 2));  mx = fmaxf(mx, __shfl_xor(mx, 1));
  float mNew = fmaxf(M, mx);
  float wt = __expf(logit - mNew);
  float f  = __expf(M - mNew);
  float ss = wt;
  ss += __shfl_xor(ss, 32); ss += __shfl_xor(ss, 16); ss += __shfl_xor(ss, 8);
  ss += __shfl_xor(ss, 4);  ss += __shfl_xor(ss, 2);  ss += __shfl_xor(ss, 1);
  Ssum = Ssum * f + ss;
  M = mNew;
  if (tid < 64) wts[lane] = wt;
  __syncthreads();

  // ---- pool from exact fp32 registers ----
  pacc *= f;
#pragma unroll
  for (int i = 0; i < 8; ++i) {
    float w = wts[tokb + 8 * i];
    pacc[0] += w * v[i][0]; pacc[1] += w * v[i][1];
    pacc[2] += w * v[i][2]; pacc[3] += w * v[i][3];
  }
}

// ---------------------------------------------------------------------------
// attn_partial: each block handles 4 chunks (stride NXB) of one batch.
// ---------------------------------------------------------------------------
__global__ __launch_bounds__(256, 2) void attn_partial(
    const float* __restrict__ seq, const int* __restrict__ lens,
    const uint16_t* __restrict__ wfrag, float* __restrict__ partials) {
  const int b    = blockIdx.y;
  const int xblk = blockIdx.x;
  const int tid  = threadIdx.x;
  const int lane = tid & 63;
  const int wv   = tid >> 6;
  const int len  = lens[b];

  __shared__ uint16_t XFhi[SUB * XSF];
  __shared__ uint16_t XFlo[SUB * XSF];
  __shared__ float lpart[4][64];
  __shared__ float wts[64];
  __shared__ f32x4 accredv[256];

  // persistent W fragments for this wave's L-tile (64 VGPR)
  s16x8 wkh[4], wkl[4], wqh[4], wql[4];
#pragma unroll
  for (int kk = 0; kk < 4; ++kk) {
    wkh[kk] = *(const s16x8*)(wfrag + (size_t)( 0 + wv * 4 + kk) * 512 + lane * 8);
    wkl[kk] = *(const s16x8*)(wfrag + (size_t)(16 + wv * 4 + kk) * 512 + lane * 8);
    wqh[kk] = *(const s16x8*)(wfrag + (size_t)(32 + wv * 4 + kk) * 512 + lane * 8);
    wql[kk] = *(const s16x8*)(wfrag + (size_t)(48 + wv * 4 + kk) * 512 + lane * 8);
  }

  for (int ci = 0; ci < CH / NXB; ++ci) {
    const int chunk  = xblk + ci * NXB;
    const int cstart = chunk * CT;
    float* rec = partials + ((size_t)b * CH + chunk) * REC;

    if (cstart >= len) {                      // fully masked: empty partial
      if (tid == 0) { rec[0] = -1e30f; rec[1] = 0.f; }
      if (tid < 32) *(f32x4*)(rec + 4 + tid * 4) = (f32x4){0.f, 0.f, 0.f, 0.f};
      continue;
    }

    const int remain = len - cstart;          // >= 1
    const int nsub = (remain > SUB) ? 2 : 1;
    const float* sp = seq + ((size_t)b * T_ + cstart) * D_;

    f32x4 vA[8], vB[8];
#pragma unroll
    for (int i = 0; i < 8; ++i) vA[i] = ((const f32x4*)sp)[tid + i * 256];

    float M = -1e30f, Ssum = 0.f;
    f32x4 pacc = (f32x4){0.f, 0.f, 0.f, 0.f};

    if (nsub == 2) {
      do_sub<true >(vA, vB, sp + SUB * D_, tid, lane, wv, cstart, len,
                    XFhi, XFlo, lpart, wts, wkh, wkl, wqh, wql, M, Ssum, pacc);
      do_sub<false>(vB, vA, nullptr, tid, lane, wv, cstart + SUB, len,
                    XFhi, XFlo, lpart, wts, wkh, wkl, wqh, wql, M, Ssum, pacc);
    } else {
      do_sub<false>(vA, vB, nullptr, tid, lane, wv, cstart, len,
                    XFhi, XFlo, lpart, wts, wkh, wkl, wqh, wql, M, Ssum, pacc);
    }

    // ---- cross-thread pool reduce + record write ----
    accredv[tid] = pacc;
    __syncthreads();
    if (tid < 32) {
      f32x4 s = accredv[tid];
#pragma unroll
      for (int k = 1; k < 8; ++k) s += accredv[tid + 32 * k];
      *(f32x4*)(rec + 4 + tid * 4) = s;
    }
    if (tid == 0) { rec[0] = M; rec[1] = Ssum; }
    // no trailing barrier needed: >=3 barriers occur before accredv reuse
  }
}

// ---------------------------------------------------------------------------
// combine: merge the 64 chunk-partials per batch, add bias.
// ---------------------------------------------------------------------------
__global__ void attn_combine(const float* __restrict__ partials,
                             const float* __restrict__ bias,
                             float* __restrict__ out) {
  int b = blockIdx.x;
  int tid = threadIdx.x;                       // 128 threads = D
  const float* base = partials + (size_t)b * CH * REC;
  float M = -1e30f;
  for (int i = 0; i < CH; ++i) M = fmaxf(M, base[i * REC]);
  float S = 0.f;
  for (int i = 0; i < CH; ++i) S += __expf(base[i * REC] - M) * base[i * REC + 1];
  float num = 0.f;
  for (int i = 0; i < CH; ++i) num += __expf(base[i * REC] - M) * base[i * REC + 4 + tid];
  float r = (S > 0.f) ? (num / S) : 0.f;       // guard: never 0/0
  out[b * D_ + tid] = r + bias[tid];
}

extern "C" void kernel_launch(void* const* d_in, const int* in_sizes, int n_in,
                              void* d_out, int out_size, void* d_ws, size_t ws_size,
                              hipStream_t stream) {
  const float* seq     = (const float*)d_in[0];
  const void*  len_raw = d_in[1];
  const float* key_w   = (const float*)d_in[2];
  const float* query_w = (const float*)d_in[3];
  const float* bias    = (const float*)d_in[4];
  float*       out     = (float*)d_out;

  uint16_t* wfrag    = (uint16_t*)d_ws;                        // 64 KB
  float*    partials = (float*)((char*)d_ws + 65536);          // ~2.1 MB
  int*      lens     = (int*)((char*)d_ws + 65536 + 2162688);

  prep<<<dim3(17), dim3(256), 0, stream>>>(key_w, query_w, len_raw, wfrag, lens);
  attn_partial<<<dim3(NXB, B_), dim3(256), 0, stream>>>(seq, lens, wfrag, partials);
  attn_combine<<<dim3(B_), dim3(128), 0, stream>>>(partials, bias, out);
}